// Round 3
// baseline (676.875 us; speedup 1.0000x reference)
//
#include <hip/hip_runtime.h>

// AutoCorrelation (Autoformer): B=4,N=207,L=96,H=8,E=64, float32 in/out.
// One block per (b,n,h). E-MAJOR lane map: e = tid&63 (lane), tau-block = wave.
// All global loads/stores and LDS accesses are wave-uniform-row + dense-lane:
// 256B coalesced, zero LDS bank conflicts, ds_read offsets fold to immediates.
// corr[tau] = sum_t q[t]*k[(t-tau)%96]; K,V tiles in LDS stride 64 (no pad).
// After corr, sK region is dead: reused for (a) V rows 96..118 duplicate
// (contiguous after sV -> wrap-free gather) and (b) a single top-4 merge buffer.
// Cross-wave top-4 merge = flat 16-candidate insertion (tb asc, slot asc scan
// preserves jax.lax.top_k smallest-index tie-break with strict > insertion).

namespace {
constexpr int Lx = 96;
constexpr int Hx = 8;
constexpr int Ex = 64;
constexpr int HE = Hx * Ex;               // 512
constexpr int NBH = 4 * 207 * Hx;         // 6624 blocks
constexpr long OUT1 = 4L * 207 * Lx * Hx * Ex;  // 40697856 elements per output
}

__global__ __launch_bounds__(256, 3) void autocorr_kernel(
    const float* __restrict__ qg,
    const float* __restrict__ kg,
    const float* __restrict__ vg,
    float* __restrict__ outV,
    float* __restrict__ outC) {
  // S layout (floats): [0,6144) = V rows 0..95 (stride 64);
  // [6144,12288) = K rows 0..95 during corr; afterwards:
  //   [6144,7616)  = V rows 96..118 (duplicate of rows 0..22, contiguous w/ sV)
  //   [8192,10240) = merge buffer (float2[16][64]: candidate-major, lane-dense)
  __shared__ __align__(16) float S[12288];
  float* sV = S;
  float* sK = S + 6144;

  const int tid = threadIdx.x;
  const int bid = blockIdx.x;
  const int bn = bid >> 3;          // (b*N+n) in [0,828)
  const int h = bid & 7;
  const int base = bn * (Lx * HE) + h * Ex;

  // ---- stage K,V into LDS [96][64], coalesced float4 reads + b128 writes ----
#pragma unroll
  for (int i = 0; i < 6; ++i) {
    int f = i * 256 + tid;          // float4 id, 0..1535 (16 per row)
    int t = f >> 4;
    int e4 = (f & 15) << 2;
    int g = base + t * HE + e4;
    float4 kv = *reinterpret_cast<const float4*>(kg + g);
    float4 vv = *reinterpret_cast<const float4*>(vg + g);
    *reinterpret_cast<float4*>(sK + t * 64 + e4) = kv;
    *reinterpret_cast<float4*>(sV + t * 64 + e4) = vv;
  }
  __syncthreads();

  const int e = tid & 63;           // lane = channel -> dense coalescing
  const int tb = tid >> 6;          // wave = tau block
  const int tau0 = tb * 24;

  float acc[24];
#pragma unroll
  for (int j = 0; j < 24; ++j) acc[j] = 0.0f;

  const float* kcol = sK + e;       // ds_read_b32 base; row*256B folds to imm
  const float* qb = qg + base + e;  // uniform base + lane offset, 256B/load

  // acc[j] = sum_u q[(u+tau0)%96] * k[(u-j)%96], u walked in 4 chunks of 24.
  // cur = k rows [24c,24c+24), prev = k rows of chunk c-1 (init: rows 72..95).
  // Ping-pong kp/ku so no register copy between chunks.
  float kp[24], ku[24];
#pragma unroll
  for (int m = 0; m < 24; ++m) kp[m] = kcol[(72 + m) * 64];

#pragma unroll 1
  for (int cc = 0; cc < 2; ++cc) {
    {
      const int c = 2 * cc;                       // cur -> ku, prev = kp
      const float* qp = qb + (24 * ((c + tb) & 3)) * HE;
      float qv[24];
#pragma unroll
      for (int tt = 0; tt < 24; ++tt) qv[tt] = qp[tt * HE];
#pragma unroll
      for (int tt = 0; tt < 24; ++tt) ku[tt] = kcol[(24 * c + tt) * 64];
#pragma unroll
      for (int tt = 0; tt < 24; ++tt) {
        float qt = qv[tt];
#pragma unroll
        for (int j = 0; j <= tt; ++j) acc[j] += qt * ku[tt - j];
#pragma unroll
        for (int j = tt + 1; j < 24; ++j) acc[j] += qt * kp[24 + tt - j];
      }
    }
    {
      const int c = 2 * cc + 1;                   // cur -> kp, prev = ku
      const float* qp = qb + (24 * ((c + tb) & 3)) * HE;
      float qv[24];
#pragma unroll
      for (int tt = 0; tt < 24; ++tt) qv[tt] = qp[tt * HE];
#pragma unroll
      for (int tt = 0; tt < 24; ++tt) kp[tt] = kcol[(24 * c + tt) * 64];
#pragma unroll
      for (int tt = 0; tt < 24; ++tt) {
        float qt = qv[tt];
#pragma unroll
        for (int j = 0; j <= tt; ++j) acc[j] += qt * kp[tt - j];
#pragma unroll
        for (int j = tt + 1; j < 24; ++j) acc[j] += qt * ku[24 + tt - j];
      }
    }
  }
  // acc[j] == corr[tau0 + j]

  // ---- local top-4 (value desc; ascending scan keeps earliest index on ties) ----
  float v0 = -__builtin_inff(), v1 = v0, v2 = v0, v3 = v0;
  int i0 = 0, i1 = 0, i2 = 0, i3 = 0;
#pragma unroll
  for (int j = 0; j < 24; ++j) {
    float nv = acc[j];
    int ni = tau0 + j;
    if (nv > v0) { v3 = v2; i3 = i2; v2 = v1; i2 = i1; v1 = v0; i1 = i0; v0 = nv; i0 = ni; }
    else if (nv > v1) { v3 = v2; i3 = i2; v2 = v1; i2 = i1; v1 = nv; i1 = ni; }
    else if (nv > v2) { v3 = v2; i3 = i2; v2 = nv; i2 = ni; }
    else if (nv > v3) { v3 = nv; i3 = ni; }
  }

  // ---- write corr now (frees acc before merge; 256B coalesced stores) ----
  {
    float* outCp = outC + base + tau0 * HE + e;
#pragma unroll
    for (int j = 0; j < 24; ++j) outCp[j * HE] = acc[j];
  }

  __syncthreads();  // all waves done reading sK; region is reusable

  // ---- post candidates: mrg[(tb*4+slot)*64 + e] = (value, index) ----
  float2* mrg = reinterpret_cast<float2*>(S + 8192);
  mrg[(tb * 4 + 0) * 64 + e] = make_float2(v0, __int_as_float(i0));
  mrg[(tb * 4 + 1) * 64 + e] = make_float2(v1, __int_as_float(i1));
  mrg[(tb * 4 + 2) * 64 + e] = make_float2(v2, __int_as_float(i2));
  mrg[(tb * 4 + 3) * 64 + e] = make_float2(v3, __int_as_float(i3));

  // duplicate V rows 0..22 into rows 96..118 (wrap-free gather): 368 float4
  {
    float4 a = *reinterpret_cast<const float4*>(S + tid * 4);
    *reinterpret_cast<float4*>(S + 6144 + tid * 4) = a;
    int i1c = tid + 256;
    if (i1c < 368) {
      float4 b = *reinterpret_cast<const float4*>(S + i1c * 4);
      *reinterpret_cast<float4*>(S + 6144 + i1c * 4) = b;
    }
  }
  __syncthreads();

  // ---- flat merge: insert all 16 candidates (tb asc, slot asc order).
  // Equal values appear in increasing-index order, so strict > insertion
  // keeps the smallest index == jax.lax.top_k tie-break.
  v0 = -__builtin_inff(); v1 = v0; v2 = v0; v3 = v0;
  i0 = 0; i1 = 0; i2 = 0; i3 = 0;
#pragma unroll
  for (int cand = 0; cand < 16; ++cand) {
    float2 c = mrg[cand * 64 + e];
    float nv = c.x;
    int ni = __float_as_int(c.y);
    if (nv > v0) { v3 = v2; i3 = i2; v2 = v1; i2 = i1; v1 = v0; i1 = i0; v0 = nv; i0 = ni; }
    else if (nv > v1) { v3 = v2; i3 = i2; v2 = v1; i2 = i1; v1 = nv; i1 = ni; }
    else if (nv > v2) { v3 = v2; i3 = i2; v2 = nv; i2 = ni; }
    else if (nv > v3) { v3 = nv; i3 = ni; }
  }

  // ---- softmax over the global top-4 ----
  float w1 = __expf(v1 - v0);
  float w2 = __expf(v2 - v0);
  float w3 = __expf(v3 - v0);
  float inv = 1.0f / (1.0f + w1 + w2 + w3);
  float w0 = inv;
  w1 *= inv; w2 *= inv; w3 *= inv;

  // ---- V: weighted circular gather, wrap-free (rows <= 118 valid) ----
  {
    int a0 = tau0 + i0; if (a0 >= 96) a0 -= 96;   // a_m in [0,95]
    int a1 = tau0 + i1; if (a1 >= 96) a1 -= 96;
    int a2 = tau0 + i2; if (a2 >= 96) a2 -= 96;
    int a3 = tau0 + i3; if (a3 >= 96) a3 -= 96;
    const float* p0 = sV + a0 * 64 + e;  // + j*256B folds to ds_read imm
    const float* p1 = sV + a1 * 64 + e;
    const float* p2 = sV + a2 * 64 + e;
    const float* p3 = sV + a3 * 64 + e;
    float* outVp = outV + base + tau0 * HE + e;
#pragma unroll
    for (int j = 0; j < 24; ++j) {
      float r = w0 * p0[j * 64];
      r += w1 * p1[j * 64];
      r += w2 * p2[j * 64];
      r += w3 * p3[j * 64];
      outVp[j * HE] = r;
    }
  }
}

extern "C" void kernel_launch(void* const* d_in, const int* in_sizes, int n_in,
                              void* d_out, int out_size, void* d_ws, size_t ws_size,
                              hipStream_t stream) {
  const float* q = (const float*)d_in[0];
  const float* k = (const float*)d_in[1];
  const float* v = (const float*)d_in[2];
  // d_in[3] = attn_mask (scalar, unused)
  float* out = (float*)d_out;               // [V | corr], each OUT1 elements
  autocorr_kernel<<<dim3(NBH), dim3(256), 0, stream>>>(q, k, v, out, out + OUT1);
}